// Round 9
// baseline (314.020 us; speedup 1.0000x reference)
//
#include <hip/hip_runtime.h>

#define D 128
#define NBB 392   // bucket array stride (>= nbkt+1)

typedef __attribute__((ext_vector_type(8))) short bf16x8;
typedef __attribute__((ext_vector_type(4))) float f32x4;

__device__ inline unsigned short f2bf(float f) {
  unsigned u = __builtin_bit_cast(unsigned, f);
  unsigned r = u + 0x7FFFu + ((u >> 16) & 1u);
  return (unsigned short)(r >> 16);
}
__device__ inline float bf2f(unsigned short b) {
  unsigned u = ((unsigned)b) << 16;
  return __builtin_bit_cast(float, u);
}

// ---------------- fp32 -> bf16 conversion, both tables in one launch ------
__global__ void __launch_bounds__(256) conv2_kernel(
    const float* __restrict__ xu, const float* __restrict__ xi,
    unsigned short* __restrict__ xbu, unsigned short* __restrict__ xbi,
    int n4u, int n4i) {
  int i = blockIdx.x * 256 + threadIdx.x;
  const float* x;
  unsigned short* xb;
  if (i < n4u) { x = xu; xb = xbu; }
  else { i -= n4u; if (i >= n4i) return; x = xi; xb = xbi; }
  float4 v = ((const float4*)x)[i];
  ushort4 o;
  o.x = f2bf(v.x); o.y = f2bf(v.y); o.z = f2bf(v.z); o.w = f2bf(v.w);
  ((ushort4*)xb)[i] = o;
}

// ---------------- coarse bucket histogram (bin = dst>>7) ------------------
struct Rel3 { const int* ei[3]; int ne[3]; int nb[3]; };

__global__ void __launch_bounds__(256) bhist_kernel(Rel3 R, int* __restrict__ bh) {
  int b = blockIdx.x, rel = 0;
  while (b >= R.nb[rel]) { b -= R.nb[rel]; rel++; }
  __shared__ int lh[NBB];
  for (int t = threadIdx.x; t < NBB; t += 256) lh[t] = 0;
  __syncthreads();
  const int ne = R.ne[rel];
  const int* dsts = R.ei[rel] + ne;
  const int base = b * 2048;
#pragma unroll
  for (int k = 0; k < 8; k++) {
    int i = base + k * 256 + threadIdx.x;
    if (i < ne) atomicAdd(&lh[dsts[i] >> 7], 1);
  }
  __syncthreads();
  for (int t = threadIdx.x; t < NBB; t += 256)
    if (lh[t]) atomicAdd(&bh[rel * NBB + t], lh[t]);
}

// ---------------- exclusive scan of bucket hist (3 waves, 1 block) --------
__global__ void __launch_bounds__(192) scanb_kernel(const int* __restrict__ bh,
                                                    int* __restrict__ bbase,
                                                    int* __restrict__ bcur, int nbkt) {
  int w = threadIdx.x >> 6, l = threadIdx.x & 63;
  if (w >= 3) return;
  const int off = w * NBB;
  int v[7];
  int s0 = 0;
#pragma unroll
  for (int k = 0; k < 7; k++) {
    int idx = l * 7 + k;
    v[k] = (idx < nbkt) ? bh[off + idx] : 0;
    s0 += v[k];
  }
  int s = s0;
  for (int dlt = 1; dlt < 64; dlt <<= 1) {
    int t = __shfl_up(s, dlt);
    if (l >= dlt) s += t;
  }
  int run = s - s0;
#pragma unroll
  for (int k = 0; k < 7; k++) {
    int idx = l * 7 + k;
    if (idx < nbkt) { bbase[off + idx] = run; bcur[off + idx] = run; run += v[k]; }
  }
  if (l == 63) bbase[off + nbkt] = run;
}

// --------- bucket partition: packed (src | (dst&127)<<25), coalesced ------
struct PArgs { const int* ei[3]; int ne[3]; int nb[3]; unsigned* part[3]; };

__global__ void __launch_bounds__(256) part_kernel(PArgs P, int* __restrict__ bcur,
                                                   int nbkt) {
  int b = blockIdx.x, rel = 0;
  while (b >= P.nb[rel]) { b -= P.nb[rel]; rel++; }
  const int ne = P.ne[rel];
  const int* src = P.ei[rel];
  const int* dst = src + ne;
  const int base = b * 4096;
  const int tn = min(4096, ne - base);
  __shared__ int lh[NBB], lscan[NBB], gb[NBB], lcur[NBB];
  __shared__ uint2 pairs[4096];
  const int tid = threadIdx.x;
  for (int t = tid; t < NBB; t += 256) lh[t] = 0;
  __syncthreads();
#pragma unroll
  for (int k = 0; k < 16; k++) {
    int i = base + k * 256 + tid;
    if (i < ne) atomicAdd(&lh[dst[i] >> 7], 1);
  }
  __syncthreads();
  if (tid < 64) {
    int v[7];
    int s0 = 0;
#pragma unroll
    for (int k = 0; k < 7; k++) {
      int idx = tid * 7 + k;
      v[k] = (idx < NBB) ? lh[idx] : 0;
      s0 += v[k];
    }
    int s = s0;
    for (int dlt = 1; dlt < 64; dlt <<= 1) {
      int t = __shfl_up(s, dlt);
      if (tid >= dlt) s += t;
    }
    int run = s - s0;
#pragma unroll
    for (int k = 0; k < 7; k++) {
      int idx = tid * 7 + k;
      if (idx < NBB) { lscan[idx] = run; run += v[k]; }
    }
  }
  __syncthreads();
  for (int t = tid; t < nbkt; t += 256) {
    gb[t] = atomicAdd(&bcur[rel * NBB + t], lh[t]);
    lcur[t] = lscan[t];
  }
  __syncthreads();
#pragma unroll
  for (int k = 0; k < 16; k++) {
    int i = base + k * 256 + tid;
    if (i < ne) {
      int d = dst[i];
      int slot = atomicAdd(&lcur[d >> 7], 1);
      pairs[slot] = (uint2){(unsigned)src[i], (unsigned)d};
    }
  }
  __syncthreads();
  unsigned* __restrict__ out = P.part[rel];
#pragma unroll
  for (int k = 0; k < 16; k++) {
    int slot = k * 256 + tid;
    if (slot < tn) {
      uint2 p = pairs[slot];
      int bin = (int)(p.y >> 7);
      out[gb[bin] + (slot - lscan[bin])] = p.x | ((p.y & 127u) << 25);
    }
  }
}

// ------ fused per-bucket sort + gather + mean (bf16 out) ------------------
struct BAArgs {
  const unsigned* part[3];
  const unsigned short* xb[3];
  unsigned short* mean[3];
  int m[3];
};

__global__ void __launch_bounds__(256) bagg_kernel(BAArgs A, const int* __restrict__ bbase,
                                                   int nbkt) {
  const int rel = blockIdx.x / nbkt;
  const int b = blockIdx.x - rel * nbkt;
  const int bs = bbase[rel * NBB + b];
  const int be = bbase[rel * NBB + b + 1];
  const int n = be - bs;
  const unsigned* __restrict__ pp = A.part[rel] + bs;
  const unsigned short* __restrict__ x = A.xb[rel];
  unsigned short* __restrict__ mean = A.mean[rel];
  const int m = A.m[rel];
  const int tid = threadIdx.x;
  const int w = tid >> 6, lane = tid & 63;
  const size_t loff = lane * 2;
  __shared__ unsigned sorted[4096];
  __shared__ int lcnt[128], lofs[128], lcur[128];

  if (n <= 4096) {
    if (tid < 128) lcnt[tid] = 0;
    __syncthreads();
    for (int i = tid; i < n; i += 256) atomicAdd(&lcnt[pp[i] >> 25], 1);
    __syncthreads();
    if (tid < 64) {
      int v0 = lcnt[2 * tid], v1 = lcnt[2 * tid + 1];
      int s0 = v0 + v1, s = s0;
      for (int dlt = 1; dlt < 64; dlt <<= 1) {
        int t = __shfl_up(s, dlt);
        if (tid >= dlt) s += t;
      }
      int ex = s - s0;
      lofs[2 * tid] = ex;
      lofs[2 * tid + 1] = ex + v0;
    }
    __syncthreads();
    if (tid < 128) lcur[tid] = lofs[tid];
    __syncthreads();
    for (int i = tid; i < n; i += 256) {
      unsigned p = pp[i];
      int slot = atomicAdd(&lcur[p >> 25], 1);
      sorted[slot] = p & 0x1FFFFFFu;
    }
    __syncthreads();
    // gather: wave w handles rows w, w+4, ...
    for (int r = w; r < 128; r += 4) {
      int gdst = b * 128 + r;
      if (gdst >= m) break;
      const int beg = lofs[r], end = lcur[r];
      float a0 = 0.f, a1 = 0.f, b0 = 0.f, b1 = 0.f;
      float c0 = 0.f, c1 = 0.f, d0 = 0.f, d1 = 0.f;
      int j = beg;
      for (; j + 4 <= end; j += 4) {
        unsigned s0 = sorted[j], s1 = sorted[j + 1], s2 = sorted[j + 2], s3 = sorted[j + 3];
        unsigned v0 = *(const unsigned*)(x + (size_t)s0 * D + loff);
        unsigned v1 = *(const unsigned*)(x + (size_t)s1 * D + loff);
        unsigned v2 = *(const unsigned*)(x + (size_t)s2 * D + loff);
        unsigned v3 = *(const unsigned*)(x + (size_t)s3 * D + loff);
        a0 += bf2f((unsigned short)(v0 & 0xFFFFu)); a1 += bf2f((unsigned short)(v0 >> 16));
        b0 += bf2f((unsigned short)(v1 & 0xFFFFu)); b1 += bf2f((unsigned short)(v1 >> 16));
        c0 += bf2f((unsigned short)(v2 & 0xFFFFu)); c1 += bf2f((unsigned short)(v2 >> 16));
        d0 += bf2f((unsigned short)(v3 & 0xFFFFu)); d1 += bf2f((unsigned short)(v3 >> 16));
      }
      for (; j < end; j++) {
        unsigned s = sorted[j];
        unsigned v = *(const unsigned*)(x + (size_t)s * D + loff);
        a0 += bf2f((unsigned short)(v & 0xFFFFu)); a1 += bf2f((unsigned short)(v >> 16));
      }
      a0 += (b0 + c0) + d0;
      a1 += (b1 + c1) + d1;
      float inv = 1.0f / (float)max(end - beg, 1);
      unsigned o = (unsigned)f2bf(a0 * inv) | ((unsigned)f2bf(a1 * inv) << 16);
      *(unsigned*)(mean + (size_t)gdst * D + loff) = o;
    }
  } else {
    // fallback (bucket > 4096 edges; never hit with uniform data): full scan
    for (int r = w; r < 128; r += 4) {
      int gdst = b * 128 + r;
      if (gdst >= m) break;
      float a0 = 0.f, a1 = 0.f;
      int cnt = 0;
      for (int j = 0; j < n; j++) {
        unsigned p = pp[j];
        if ((int)(p >> 25) == r) {
          unsigned v = *(const unsigned*)(x + (size_t)(p & 0x1FFFFFFu) * D + loff);
          a0 += bf2f((unsigned short)(v & 0xFFFFu));
          a1 += bf2f((unsigned short)(v >> 16));
          cnt++;
        }
      }
      float inv = 1.0f / (float)max(cnt, 1);
      unsigned o = (unsigned)f2bf(a0 * inv) | ((unsigned)f2bf(a1 * inv) << 16);
      *(unsigned*)(mean + (size_t)gdst * D + loff) = o;
    }
  }
}

// ---------------- prep: combined bf16 weights (n-major) + biases ----------
__global__ void __launch_bounds__(384) prep_kernel(
    const float* __restrict__ Wl_rates, const float* __restrict__ Wr_rates, const float* __restrict__ bl_rates,
    const float* __restrict__ Wl_rev, const float* __restrict__ Wr_rev, const float* __restrict__ bl_rev,
    const float* __restrict__ Wl_fol, const float* __restrict__ Wr_fol, const float* __restrict__ bl_fol,
    unsigned short* __restrict__ Wb_user, unsigned short* __restrict__ Wb_item,
    float* __restrict__ b_user, float* __restrict__ b_item) {
  int n = blockIdx.x;          // 0..127
  int k = threadIdx.x;         // 0..383
  float v;
  if (k < 128)      v = 0.5f * Wl_rev[n * 128 + k];
  else if (k < 256) v = 0.5f * Wl_fol[n * 128 + (k - 128)];
  else              v = 0.5f * (Wr_rev[n * 128 + (k - 256)] + Wr_fol[n * 128 + (k - 256)]);
  Wb_user[n * 384 + k] = f2bf(v);
  if (k < 256) {
    float w = (k < 128) ? Wl_rates[n * 128 + k] : Wr_rates[n * 128 + (k - 128)];
    Wb_item[n * 256 + k] = f2bf(w);
  }
  if (n == 0 && k < 128) {
    b_item[k] = bl_rates[k];
    b_user[k] = 0.5f * (bl_rev[k] + bl_fol[k]);
  }
}

// -------- bf16 MFMA GEMM, 128x128 tile, both outputs in one launch --------
struct BSrcs { const unsigned short* s[3]; };
struct GemmArgs {
  BSrcs su, si;
  const unsigned short* wbU; const unsigned short* wbI;
  const float* bU; const float* bI;
  float* outU; float* outI;
  int MU, MI, nbU;
};

__global__ void __launch_bounds__(256) gemm2_kernel(GemmArgs A) {
  const bool isU = (int)blockIdx.x < A.nbU;
  const int bid = isU ? blockIdx.x : blockIdx.x - A.nbU;
  const BSrcs S = isU ? A.su : A.si;
  const unsigned short* __restrict__ Wb = isU ? A.wbU : A.wbI;
  const int K = isU ? 384 : 256;
  const float* __restrict__ bias = isU ? A.bU : A.bI;
  float* __restrict__ out = isU ? A.outU : A.outI;
  const int M = isU ? A.MU : A.MI;

  __shared__ __align__(16) unsigned short As[128][72];
  __shared__ __align__(16) unsigned short Ws[128][72];
  const int tid = threadIdx.x;
  const int lane = tid & 63;
  const int wave = tid >> 6;
  const int wr = (wave >> 1) * 64;   // wave row base
  const int wc = (wave & 1) * 64;    // wave col base
  const int l15 = lane & 15;
  const int quad = lane >> 4;
  const int m0 = bid * 128;

  f32x4 acc[4][4];
#pragma unroll
  for (int r = 0; r < 4; r++)
#pragma unroll
    for (int c = 0; c < 4; c++) acc[r][c] = (f32x4){0.f, 0.f, 0.f, 0.f};

  const int srow = tid >> 1, shalf = tid & 1;   // staging: 128 rows x 2 halves (32 shorts each)
  const int nchunks = K >> 6;
  for (int ch = 0; ch < nchunks; ch++) {
    const unsigned short* sp = S.s[ch >> 1];
    const int coff = (ch & 1) << 6;
    {
      int mm = min(m0 + srow, M - 1);   // clamp: dup rows harmless, outputs guarded
      const uint4* g = (const uint4*)(sp + (size_t)mm * D + coff + shalf * 32);
      uint4* ld = (uint4*)(&As[srow][shalf * 32]);
      ld[0] = g[0]; ld[1] = g[1]; ld[2] = g[2]; ld[3] = g[3];
    }
    {
      const uint4* g = (const uint4*)(Wb + (size_t)srow * K + ch * 64 + shalf * 32);
      uint4* ld = (uint4*)(&Ws[srow][shalf * 32]);
      ld[0] = g[0]; ld[1] = g[1]; ld[2] = g[2]; ld[3] = g[3];
    }
    __syncthreads();
#pragma unroll
    for (int kk = 0; kk < 64; kk += 32) {
      const int kb = kk + quad * 8;
      bf16x8 a0 = *(const bf16x8*)&As[wr + l15][kb];
      bf16x8 a1 = *(const bf16x8*)&As[wr + 16 + l15][kb];
      bf16x8 a2 = *(const bf16x8*)&As[wr + 32 + l15][kb];
      bf16x8 a3 = *(const bf16x8*)&As[wr + 48 + l15][kb];
      bf16x8 b0 = *(const bf16x8*)&Ws[wc + l15][kb];
      bf16x8 b1 = *(const bf16x8*)&Ws[wc + 16 + l15][kb];
      bf16x8 b2 = *(const bf16x8*)&Ws[wc + 32 + l15][kb];
      bf16x8 b3 = *(const bf16x8*)&Ws[wc + 48 + l15][kb];
      acc[0][0] = __builtin_amdgcn_mfma_f32_16x16x32_bf16(a0, b0, acc[0][0], 0, 0, 0);
      acc[0][1] = __builtin_amdgcn_mfma_f32_16x16x32_bf16(a0, b1, acc[0][1], 0, 0, 0);
      acc[0][2] = __builtin_amdgcn_mfma_f32_16x16x32_bf16(a0, b2, acc[0][2], 0, 0, 0);
      acc[0][3] = __builtin_amdgcn_mfma_f32_16x16x32_bf16(a0, b3, acc[0][3], 0, 0, 0);
      acc[1][0] = __builtin_amdgcn_mfma_f32_16x16x32_bf16(a1, b0, acc[1][0], 0, 0, 0);
      acc[1][1] = __builtin_amdgcn_mfma_f32_16x16x32_bf16(a1, b1, acc[1][1], 0, 0, 0);
      acc[1][2] = __builtin_amdgcn_mfma_f32_16x16x32_bf16(a1, b2, acc[1][2], 0, 0, 0);
      acc[1][3] = __builtin_amdgcn_mfma_f32_16x16x32_bf16(a1, b3, acc[1][3], 0, 0, 0);
      acc[2][0] = __builtin_amdgcn_mfma_f32_16x16x32_bf16(a2, b0, acc[2][0], 0, 0, 0);
      acc[2][1] = __builtin_amdgcn_mfma_f32_16x16x32_bf16(a2, b1, acc[2][1], 0, 0, 0);
      acc[2][2] = __builtin_amdgcn_mfma_f32_16x16x32_bf16(a2, b2, acc[2][2], 0, 0, 0);
      acc[2][3] = __builtin_amdgcn_mfma_f32_16x16x32_bf16(a2, b3, acc[2][3], 0, 0, 0);
      acc[3][0] = __builtin_amdgcn_mfma_f32_16x16x32_bf16(a3, b0, acc[3][0], 0, 0, 0);
      acc[3][1] = __builtin_amdgcn_mfma_f32_16x16x32_bf16(a3, b1, acc[3][1], 0, 0, 0);
      acc[3][2] = __builtin_amdgcn_mfma_f32_16x16x32_bf16(a3, b2, acc[3][2], 0, 0, 0);
      acc[3][3] = __builtin_amdgcn_mfma_f32_16x16x32_bf16(a3, b3, acc[3][3], 0, 0, 0);
    }
    __syncthreads();
  }
#pragma unroll
  for (int c = 0; c < 4; c++) {
    const int n = wc + c * 16 + l15;
    const float bv = bias[n];
#pragma unroll
    for (int r = 0; r < 4; r++) {
      const int mrow = m0 + wr + r * 16 + quad * 4;
#pragma unroll
      for (int i = 0; i < 4; i++) {
        if (mrow + i < M) out[(size_t)(mrow + i) * D + n] = acc[r][c][i] + bv;
      }
    }
  }
}

extern "C" void kernel_launch(void* const* d_in, const int* in_sizes, int n_in,
                              void* d_out, int out_size, void* d_ws, size_t ws_size,
                              hipStream_t stream) {
  const float* x_user   = (const float*)d_in[0];
  const float* x_item   = (const float*)d_in[1];
  const int*   ei_rates = (const int*)d_in[2];
  const int*   ei_rev   = (const int*)d_in[3];
  const int*   ei_fol   = (const int*)d_in[4];
  const float* Wl_rates = (const float*)d_in[5];
  const float* bl_rates = (const float*)d_in[6];
  const float* Wr_rates = (const float*)d_in[7];
  const float* Wl_rev   = (const float*)d_in[8];
  const float* bl_rev   = (const float*)d_in[9];
  const float* Wr_rev   = (const float*)d_in[10];
  const float* Wl_fol   = (const float*)d_in[11];
  const float* bl_fol   = (const float*)d_in[12];
  const float* Wr_fol   = (const float*)d_in[13];

  const int NU = in_sizes[0] / D;       // 50000
  const int NI = in_sizes[1] / D;       // 50000
  const int E_rates = in_sizes[2] / 2;
  const int E_rev   = in_sizes[3] / 2;
  const int E_fol   = in_sizes[4] / 2;
  const int nbkt = ((NU > NI ? NU : NI) + 127) / 128;   // 391

  // ---- workspace carve-up (byte-based, 16B aligned) ----
  char* wsb = (char*)d_ws;
  size_t off = 0;
  auto take = [&](size_t bytes) {
    char* p = wsb + off;
    off += (bytes + 15) & ~(size_t)15;
    return p;
  };
  int* bhist = (int*)take(3 * NBB * 4);          // zeroed
  const size_t zero_bytes = off;
  int* bbase = (int*)take(3 * NBB * 4);
  int* bcur  = (int*)take(3 * NBB * 4);
  unsigned* part_rates = (unsigned*)take((size_t)E_rates * 4);
  unsigned* part_rev   = (unsigned*)take((size_t)E_rev * 4);
  unsigned* part_fol   = (unsigned*)take((size_t)E_fol * 4);
  unsigned short* xb_user    = (unsigned short*)take((size_t)NU * D * 2);
  unsigned short* xb_item    = (unsigned short*)take((size_t)NI * D * 2);
  unsigned short* mean_rates = (unsigned short*)take((size_t)NI * D * 2);
  unsigned short* mean_rev   = (unsigned short*)take((size_t)NU * D * 2);
  unsigned short* mean_fol   = (unsigned short*)take((size_t)NU * D * 2);
  unsigned short* Wb_user    = (unsigned short*)take(128 * 384 * 2);
  unsigned short* Wb_item    = (unsigned short*)take(128 * 256 * 2);
  float* b_user = (float*)take(128 * 4);
  float* b_item = (float*)take(128 * 4);

  hipMemsetAsync(d_ws, 0, zero_bytes, stream);
  prep_kernel<<<128, 384, 0, stream>>>(Wl_rates, Wr_rates, bl_rates,
                                       Wl_rev, Wr_rev, bl_rev,
                                       Wl_fol, Wr_fol, bl_fol,
                                       Wb_user, Wb_item, b_user, b_item);
  {
    int n4u = NU * D / 4, n4i = NI * D / 4;
    conv2_kernel<<<(n4u + n4i + 255) / 256, 256, 0, stream>>>(
        x_user, x_item, xb_user, xb_item, n4u, n4i);
  }

  Rel3 R;
  R.ei[0] = ei_rates; R.ne[0] = E_rates; R.nb[0] = (E_rates + 2047) / 2048;
  R.ei[1] = ei_rev;   R.ne[1] = E_rev;   R.nb[1] = (E_rev + 2047) / 2048;
  R.ei[2] = ei_fol;   R.ne[2] = E_fol;   R.nb[2] = (E_fol + 2047) / 2048;
  bhist_kernel<<<R.nb[0] + R.nb[1] + R.nb[2], 256, 0, stream>>>(R, bhist);

  scanb_kernel<<<1, 192, 0, stream>>>(bhist, bbase, bcur, nbkt);

  PArgs P;
  P.ei[0] = ei_rates; P.ne[0] = E_rates; P.nb[0] = (E_rates + 4095) / 4096; P.part[0] = part_rates;
  P.ei[1] = ei_rev;   P.ne[1] = E_rev;   P.nb[1] = (E_rev + 4095) / 4096;   P.part[1] = part_rev;
  P.ei[2] = ei_fol;   P.ne[2] = E_fol;   P.nb[2] = (E_fol + 4095) / 4096;   P.part[2] = part_fol;
  part_kernel<<<P.nb[0] + P.nb[1] + P.nb[2], 256, 0, stream>>>(P, bcur, nbkt);

  BAArgs BA;
  BA.part[0] = part_rates; BA.xb[0] = xb_user; BA.mean[0] = mean_rates; BA.m[0] = NI;
  BA.part[1] = part_rev;   BA.xb[1] = xb_item; BA.mean[1] = mean_rev;   BA.m[1] = NU;
  BA.part[2] = part_fol;   BA.xb[2] = xb_user; BA.mean[2] = mean_fol;   BA.m[2] = NU;
  bagg_kernel<<<3 * nbkt, 256, 0, stream>>>(BA, bbase, nbkt);

  GemmArgs gma;
  gma.su.s[0] = mean_rev;   gma.su.s[1] = mean_fol; gma.su.s[2] = xb_user;
  gma.si.s[0] = mean_rates; gma.si.s[1] = xb_item;  gma.si.s[2] = nullptr;
  gma.wbU = Wb_user; gma.wbI = Wb_item;
  gma.bU = b_user;   gma.bI = b_item;
  gma.outU = (float*)d_out;
  gma.outI = (float*)d_out + (size_t)NU * D;
  gma.MU = NU; gma.MI = NI;
  gma.nbU = (NU + 127) / 128;
  const int nbI = (NI + 127) / 128;
  gemm2_kernel<<<gma.nbU + nbI, 256, 0, stream>>>(gma);
}

// Round 10
// 306.120 us; speedup vs baseline: 1.0258x; 1.0258x over previous
//
#include <hip/hip_runtime.h>

#define D 128
#define NBB 392   // bucket array stride (>= nbkt+1)

typedef __attribute__((ext_vector_type(8))) short bf16x8;
typedef __attribute__((ext_vector_type(4))) float f32x4;

__device__ inline unsigned short f2bf(float f) {
  unsigned u = __builtin_bit_cast(unsigned, f);
  unsigned r = u + 0x7FFFu + ((u >> 16) & 1u);
  return (unsigned short)(r >> 16);
}
__device__ inline float bf2f(unsigned short b) {
  unsigned u = ((unsigned)b) << 16;
  return __builtin_bit_cast(float, u);
}

// ------- fused setup: conv (fp32->bf16) | bucket hist | weight prep -------
struct SetupArgs {
  // conv
  const float* xu; const float* xi;
  unsigned short* xbu; unsigned short* xbi;
  int n4u, n4i, nbConv;
  // bhist
  const int* ei[3]; int ne[3]; int nbh[3]; int nbHist;
  int* bh;
  // prep
  const float* Wl_rates; const float* Wr_rates; const float* bl_rates;
  const float* Wl_rev;   const float* Wr_rev;   const float* bl_rev;
  const float* Wl_fol;   const float* Wr_fol;   const float* bl_fol;
  unsigned short* Wb_user; unsigned short* Wb_item;
  float* b_user; float* b_item;
};

__global__ void __launch_bounds__(256) setup_kernel(SetupArgs S) {
  const int tid = threadIdx.x;
  int b = blockIdx.x;
  if (b < S.nbConv) {
    int i = b * 256 + tid;
    const float* x;
    unsigned short* xb;
    if (i < S.n4u) { x = S.xu; xb = S.xbu; }
    else { i -= S.n4u; if (i >= S.n4i) return; x = S.xi; xb = S.xbi; }
    float4 v = ((const float4*)x)[i];
    ushort4 o;
    o.x = f2bf(v.x); o.y = f2bf(v.y); o.z = f2bf(v.z); o.w = f2bf(v.w);
    ((ushort4*)xb)[i] = o;
    return;
  }
  b -= S.nbConv;
  if (b < S.nbHist) {
    int rel = 0;
    while (b >= S.nbh[rel]) { b -= S.nbh[rel]; rel++; }
    __shared__ int lh[NBB];
    for (int t = tid; t < NBB; t += 256) lh[t] = 0;
    __syncthreads();
    const int ne = S.ne[rel];
    const int* dsts = S.ei[rel] + ne;
    const int base = b * 2048;
#pragma unroll
    for (int k = 0; k < 8; k++) {
      int i = base + k * 256 + tid;
      if (i < ne) atomicAdd(&lh[dsts[i] >> 7], 1);
    }
    __syncthreads();
    for (int t = tid; t < NBB; t += 256)
      if (lh[t]) atomicAdd(&S.bh[rel * NBB + t], lh[t]);
    return;
  }
  b -= S.nbHist;
  // prep: 192 blocks x 256 thr covering 128*384 elements
  int idx = b * 256 + tid;
  if (idx >= 128 * 384) return;
  int n = idx / 384, k = idx - n * 384;
  float v;
  if (k < 128)      v = 0.5f * S.Wl_rev[n * 128 + k];
  else if (k < 256) v = 0.5f * S.Wl_fol[n * 128 + (k - 128)];
  else              v = 0.5f * (S.Wr_rev[n * 128 + (k - 256)] + S.Wr_fol[n * 128 + (k - 256)]);
  S.Wb_user[n * 384 + k] = f2bf(v);
  if (k < 256) {
    float w = (k < 128) ? S.Wl_rates[n * 128 + k] : S.Wr_rates[n * 128 + (k - 128)];
    S.Wb_item[n * 256 + k] = f2bf(w);
  }
  if (idx < 128) {
    S.b_item[idx] = S.bl_rates[idx];
    S.b_user[idx] = 0.5f * (S.bl_rev[idx] + S.bl_fol[idx]);
  }
}

// ---------------- exclusive scan of bucket hist (3 waves, 1 block) --------
__global__ void __launch_bounds__(192) scanb_kernel(const int* __restrict__ bh,
                                                    int* __restrict__ bbase,
                                                    int* __restrict__ bcur, int nbkt) {
  int w = threadIdx.x >> 6, l = threadIdx.x & 63;
  if (w >= 3) return;
  const int off = w * NBB;
  int v[7];
  int s0 = 0;
#pragma unroll
  for (int k = 0; k < 7; k++) {
    int idx = l * 7 + k;
    v[k] = (idx < nbkt) ? bh[off + idx] : 0;
    s0 += v[k];
  }
  int s = s0;
  for (int dlt = 1; dlt < 64; dlt <<= 1) {
    int t = __shfl_up(s, dlt);
    if (l >= dlt) s += t;
  }
  int run = s - s0;
#pragma unroll
  for (int k = 0; k < 7; k++) {
    int idx = l * 7 + k;
    if (idx < nbkt) { bbase[off + idx] = run; bcur[off + idx] = run; run += v[k]; }
  }
  if (l == 63) bbase[off + nbkt] = run;
}

// --------- bucket partition: packed (src | (dst&127)<<25), coalesced ------
struct PArgs { const int* ei[3]; int ne[3]; int nb[3]; unsigned* part[3]; };

__global__ void __launch_bounds__(256) part_kernel(PArgs P, int* __restrict__ bcur,
                                                   int nbkt) {
  int b = blockIdx.x, rel = 0;
  while (b >= P.nb[rel]) { b -= P.nb[rel]; rel++; }
  const int ne = P.ne[rel];
  const int* src = P.ei[rel];
  const int* dst = src + ne;
  const int base = b * 4096;
  const int tn = min(4096, ne - base);
  __shared__ int lh[NBB], lscan[NBB], gb[NBB], lcur[NBB];
  __shared__ uint2 pairs[4096];
  const int tid = threadIdx.x;
  for (int t = tid; t < NBB; t += 256) lh[t] = 0;
  __syncthreads();
#pragma unroll
  for (int k = 0; k < 16; k++) {
    int i = base + k * 256 + tid;
    if (i < ne) atomicAdd(&lh[dst[i] >> 7], 1);
  }
  __syncthreads();
  if (tid < 64) {
    int v[7];
    int s0 = 0;
#pragma unroll
    for (int k = 0; k < 7; k++) {
      int idx = tid * 7 + k;
      v[k] = (idx < NBB) ? lh[idx] : 0;
      s0 += v[k];
    }
    int s = s0;
    for (int dlt = 1; dlt < 64; dlt <<= 1) {
      int t = __shfl_up(s, dlt);
      if (tid >= dlt) s += t;
    }
    int run = s - s0;
#pragma unroll
    for (int k = 0; k < 7; k++) {
      int idx = tid * 7 + k;
      if (idx < NBB) { lscan[idx] = run; run += v[k]; }
    }
  }
  __syncthreads();
  for (int t = tid; t < nbkt; t += 256) {
    gb[t] = atomicAdd(&bcur[rel * NBB + t], lh[t]);
    lcur[t] = lscan[t];
  }
  __syncthreads();
#pragma unroll
  for (int k = 0; k < 16; k++) {
    int i = base + k * 256 + tid;
    if (i < ne) {
      int d = dst[i];
      int slot = atomicAdd(&lcur[d >> 7], 1);
      pairs[slot] = (uint2){(unsigned)src[i], (unsigned)d};
    }
  }
  __syncthreads();
  unsigned* __restrict__ out = P.part[rel];
#pragma unroll
  for (int k = 0; k < 16; k++) {
    int slot = k * 256 + tid;
    if (slot < tn) {
      uint2 p = pairs[slot];
      int bin = (int)(p.y >> 7);
      out[gb[bin] + (slot - lscan[bin])] = p.x | ((p.y & 127u) << 25);
    }
  }
}

// ------ fused per-bucket sort + gather + mean (bf16 out), dual-row MLP ----
struct BAArgs {
  const unsigned* part[3];
  const unsigned short* xb[3];
  unsigned short* mean[3];
  int m[3];
};

__global__ void __launch_bounds__(256) bagg_kernel(BAArgs A, const int* __restrict__ bbase,
                                                   int nbkt) {
  const int rel = blockIdx.x / nbkt;
  const int b = blockIdx.x - rel * nbkt;
  const int bs = bbase[rel * NBB + b];
  const int be = bbase[rel * NBB + b + 1];
  const int n = be - bs;
  const unsigned* __restrict__ pp = A.part[rel] + bs;
  const unsigned short* __restrict__ x = A.xb[rel];
  unsigned short* __restrict__ mean = A.mean[rel];
  const int m = A.m[rel];
  const int tid = threadIdx.x;
  const int w = tid >> 6, lane = tid & 63;
  const size_t loff = lane * 2;
  __shared__ unsigned sorted[4096];
  __shared__ int lcnt[128], lofs[128], lcur[128];

  if (n > 4096) {   // fallback (never hit with uniform data): full scan
    for (int r = w; r < 128; r += 4) {
      int gdst = b * 128 + r;
      if (gdst >= m) break;
      float a0 = 0.f, a1 = 0.f;
      int cnt = 0;
      for (int j = 0; j < n; j++) {
        unsigned p = pp[j];
        if ((int)(p >> 25) == r) {
          unsigned v = *(const unsigned*)(x + (size_t)(p & 0x1FFFFFFu) * D + loff);
          a0 += bf2f((unsigned short)(v & 0xFFFFu));
          a1 += bf2f((unsigned short)(v >> 16));
          cnt++;
        }
      }
      float inv = 1.0f / (float)max(cnt, 1);
      unsigned o = (unsigned)f2bf(a0 * inv) | ((unsigned)f2bf(a1 * inv) << 16);
      *(unsigned*)(mean + (size_t)gdst * D + loff) = o;
    }
    return;
  }

  if (tid < 128) lcnt[tid] = 0;
  __syncthreads();
  for (int i = tid; i < n; i += 256) atomicAdd(&lcnt[pp[i] >> 25], 1);
  __syncthreads();
  if (tid < 64) {
    int v0 = lcnt[2 * tid], v1 = lcnt[2 * tid + 1];
    int s0 = v0 + v1, s = s0;
    for (int dlt = 1; dlt < 64; dlt <<= 1) {
      int t = __shfl_up(s, dlt);
      if (tid >= dlt) s += t;
    }
    int ex = s - s0;
    lofs[2 * tid] = ex;
    lofs[2 * tid + 1] = ex + v0;
  }
  __syncthreads();
  if (tid < 128) lcur[tid] = lofs[tid];
  __syncthreads();
  for (int i = tid; i < n; i += 256) {
    unsigned p = pp[i];
    int slot = atomicAdd(&lcur[p >> 25], 1);
    sorted[slot] = p & 0x1FFFFFFu;
  }
  __syncthreads();

  // gather: wave w handles row pairs (r, r+4) for r = w, w+8, ... (8 loads in flight)
  for (int r = w; r < 128; r += 8) {
    const int rA = r, rB = r + 4;
    const int gA = b * 128 + rA, gB = b * 128 + rB;
    if (gA >= m) break;
    const bool doB = gB < m;
    int jA = lofs[rA];
    const int eA = lcur[rA];
    int jB = doB ? lofs[rB] : 0;
    const int eB = doB ? lcur[rB] : 0;
    float aA0=0,aA1=0,bA0=0,bA1=0,cA0=0,cA1=0,dA0=0,dA1=0;
    float aB0=0,aB1=0,bB0=0,bB1=0,cB0=0,cB1=0,dB0=0,dB1=0;
    // dual-row main loop: 8 independent loads
    while (jA + 4 <= eA && jB + 4 <= eB) {
      unsigned sA0 = sorted[jA], sA1 = sorted[jA+1], sA2 = sorted[jA+2], sA3 = sorted[jA+3];
      unsigned sB0 = sorted[jB], sB1 = sorted[jB+1], sB2 = sorted[jB+2], sB3 = sorted[jB+3];
      unsigned vA0 = *(const unsigned*)(x + (size_t)sA0 * D + loff);
      unsigned vA1 = *(const unsigned*)(x + (size_t)sA1 * D + loff);
      unsigned vA2 = *(const unsigned*)(x + (size_t)sA2 * D + loff);
      unsigned vA3 = *(const unsigned*)(x + (size_t)sA3 * D + loff);
      unsigned vB0 = *(const unsigned*)(x + (size_t)sB0 * D + loff);
      unsigned vB1 = *(const unsigned*)(x + (size_t)sB1 * D + loff);
      unsigned vB2 = *(const unsigned*)(x + (size_t)sB2 * D + loff);
      unsigned vB3 = *(const unsigned*)(x + (size_t)sB3 * D + loff);
      aA0 += bf2f((unsigned short)(vA0 & 0xFFFFu)); aA1 += bf2f((unsigned short)(vA0 >> 16));
      bA0 += bf2f((unsigned short)(vA1 & 0xFFFFu)); bA1 += bf2f((unsigned short)(vA1 >> 16));
      cA0 += bf2f((unsigned short)(vA2 & 0xFFFFu)); cA1 += bf2f((unsigned short)(vA2 >> 16));
      dA0 += bf2f((unsigned short)(vA3 & 0xFFFFu)); dA1 += bf2f((unsigned short)(vA3 >> 16));
      aB0 += bf2f((unsigned short)(vB0 & 0xFFFFu)); aB1 += bf2f((unsigned short)(vB0 >> 16));
      bB0 += bf2f((unsigned short)(vB1 & 0xFFFFu)); bB1 += bf2f((unsigned short)(vB1 >> 16));
      cB0 += bf2f((unsigned short)(vB2 & 0xFFFFu)); cB1 += bf2f((unsigned short)(vB2 >> 16));
      dB0 += bf2f((unsigned short)(vB3 & 0xFFFFu)); dB1 += bf2f((unsigned short)(vB3 >> 16));
      jA += 4; jB += 4;
    }
    // drain A
    for (; jA + 4 <= eA; jA += 4) {
      unsigned s0 = sorted[jA], s1 = sorted[jA+1], s2 = sorted[jA+2], s3 = sorted[jA+3];
      unsigned v0 = *(const unsigned*)(x + (size_t)s0 * D + loff);
      unsigned v1 = *(const unsigned*)(x + (size_t)s1 * D + loff);
      unsigned v2 = *(const unsigned*)(x + (size_t)s2 * D + loff);
      unsigned v3 = *(const unsigned*)(x + (size_t)s3 * D + loff);
      aA0 += bf2f((unsigned short)(v0 & 0xFFFFu)); aA1 += bf2f((unsigned short)(v0 >> 16));
      bA0 += bf2f((unsigned short)(v1 & 0xFFFFu)); bA1 += bf2f((unsigned short)(v1 >> 16));
      cA0 += bf2f((unsigned short)(v2 & 0xFFFFu)); cA1 += bf2f((unsigned short)(v2 >> 16));
      dA0 += bf2f((unsigned short)(v3 & 0xFFFFu)); dA1 += bf2f((unsigned short)(v3 >> 16));
    }
    for (; jA < eA; jA++) {
      unsigned s = sorted[jA];
      unsigned v = *(const unsigned*)(x + (size_t)s * D + loff);
      aA0 += bf2f((unsigned short)(v & 0xFFFFu)); aA1 += bf2f((unsigned short)(v >> 16));
    }
    // drain B
    for (; jB + 4 <= eB; jB += 4) {
      unsigned s0 = sorted[jB], s1 = sorted[jB+1], s2 = sorted[jB+2], s3 = sorted[jB+3];
      unsigned v0 = *(const unsigned*)(x + (size_t)s0 * D + loff);
      unsigned v1 = *(const unsigned*)(x + (size_t)s1 * D + loff);
      unsigned v2 = *(const unsigned*)(x + (size_t)s2 * D + loff);
      unsigned v3 = *(const unsigned*)(x + (size_t)s3 * D + loff);
      aB0 += bf2f((unsigned short)(v0 & 0xFFFFu)); aB1 += bf2f((unsigned short)(v0 >> 16));
      bB0 += bf2f((unsigned short)(v1 & 0xFFFFu)); bB1 += bf2f((unsigned short)(v1 >> 16));
      cB0 += bf2f((unsigned short)(v2 & 0xFFFFu)); cB1 += bf2f((unsigned short)(v2 >> 16));
      dB0 += bf2f((unsigned short)(v3 & 0xFFFFu)); dB1 += bf2f((unsigned short)(v3 >> 16));
    }
    for (; jB < eB; jB++) {
      unsigned s = sorted[jB];
      unsigned v = *(const unsigned*)(x + (size_t)s * D + loff);
      aB0 += bf2f((unsigned short)(v & 0xFFFFu)); aB1 += bf2f((unsigned short)(v >> 16));
    }
    // write A
    {
      float v0 = (aA0 + bA0) + (cA0 + dA0);
      float v1 = (aA1 + bA1) + (cA1 + dA1);
      float inv = 1.0f / (float)max(eA - lofs[rA], 1);
      unsigned o = (unsigned)f2bf(v0 * inv) | ((unsigned)f2bf(v1 * inv) << 16);
      *(unsigned*)(mean + (size_t)gA * D + loff) = o;
    }
    if (doB) {
      float v0 = (aB0 + bB0) + (cB0 + dB0);
      float v1 = (aB1 + bB1) + (cB1 + dB1);
      float inv = 1.0f / (float)max(eB - lofs[rB], 1);
      unsigned o = (unsigned)f2bf(v0 * inv) | ((unsigned)f2bf(v1 * inv) << 16);
      *(unsigned*)(mean + (size_t)gB * D + loff) = o;
    }
  }
}

// -------- bf16 MFMA GEMM, 128x128 tile, both outputs in one launch --------
struct BSrcs { const unsigned short* s[3]; };
struct GemmArgs {
  BSrcs su, si;
  const unsigned short* wbU; const unsigned short* wbI;
  const float* bU; const float* bI;
  float* outU; float* outI;
  int MU, MI, nbU;
};

__global__ void __launch_bounds__(256) gemm2_kernel(GemmArgs A) {
  const bool isU = (int)blockIdx.x < A.nbU;
  const int bid = isU ? blockIdx.x : blockIdx.x - A.nbU;
  const BSrcs S = isU ? A.su : A.si;
  const unsigned short* __restrict__ Wb = isU ? A.wbU : A.wbI;
  const int K = isU ? 384 : 256;
  const float* __restrict__ bias = isU ? A.bU : A.bI;
  float* __restrict__ out = isU ? A.outU : A.outI;
  const int M = isU ? A.MU : A.MI;

  __shared__ __align__(16) unsigned short As[128][72];
  __shared__ __align__(16) unsigned short Ws[128][72];
  const int tid = threadIdx.x;
  const int lane = tid & 63;
  const int wave = tid >> 6;
  const int wr = (wave >> 1) * 64;   // wave row base
  const int wc = (wave & 1) * 64;    // wave col base
  const int l15 = lane & 15;
  const int quad = lane >> 4;
  const int m0 = bid * 128;

  f32x4 acc[4][4];
#pragma unroll
  for (int r = 0; r < 4; r++)
#pragma unroll
    for (int c = 0; c < 4; c++) acc[r][c] = (f32x4){0.f, 0.f, 0.f, 0.f};

  const int srow = tid >> 1, shalf = tid & 1;   // staging: 128 rows x 2 halves (32 shorts each)
  const int nchunks = K >> 6;
  for (int ch = 0; ch < nchunks; ch++) {
    const unsigned short* sp = S.s[ch >> 1];
    const int coff = (ch & 1) << 6;
    {
      int mm = min(m0 + srow, M - 1);   // clamp: dup rows harmless, outputs guarded
      const uint4* g = (const uint4*)(sp + (size_t)mm * D + coff + shalf * 32);
      uint4* ld = (uint4*)(&As[srow][shalf * 32]);
      ld[0] = g[0]; ld[1] = g[1]; ld[2] = g[2]; ld[3] = g[3];
    }
    {
      const uint4* g = (const uint4*)(Wb + (size_t)srow * K + ch * 64 + shalf * 32);
      uint4* ld = (uint4*)(&Ws[srow][shalf * 32]);
      ld[0] = g[0]; ld[1] = g[1]; ld[2] = g[2]; ld[3] = g[3];
    }
    __syncthreads();
#pragma unroll
    for (int kk = 0; kk < 64; kk += 32) {
      const int kb = kk + quad * 8;
      bf16x8 a0 = *(const bf16x8*)&As[wr + l15][kb];
      bf16x8 a1 = *(const bf16x8*)&As[wr + 16 + l15][kb];
      bf16x8 a2 = *(const bf16x8*)&As[wr + 32 + l15][kb];
      bf16x8 a3 = *(const bf16x8*)&As[wr + 48 + l15][kb];
      bf16x8 b0 = *(const bf16x8*)&Ws[wc + l15][kb];
      bf16x8 b1 = *(const bf16x8*)&Ws[wc + 16 + l15][kb];
      bf16x8 b2 = *(const bf16x8*)&Ws[wc + 32 + l15][kb];
      bf16x8 b3 = *(const bf16x8*)&Ws[wc + 48 + l15][kb];
      acc[0][0] = __builtin_amdgcn_mfma_f32_16x16x32_bf16(a0, b0, acc[0][0], 0, 0, 0);
      acc[0][1] = __builtin_amdgcn_mfma_f32_16x16x32_bf16(a0, b1, acc[0][1], 0, 0, 0);
      acc[0][2] = __builtin_amdgcn_mfma_f32_16x16x32_bf16(a0, b2, acc[0][2], 0, 0, 0);
      acc[0][3] = __builtin_amdgcn_mfma_f32_16x16x32_bf16(a0, b3, acc[0][3], 0, 0, 0);
      acc[1][0] = __builtin_amdgcn_mfma_f32_16x16x32_bf16(a1, b0, acc[1][0], 0, 0, 0);
      acc[1][1] = __builtin_amdgcn_mfma_f32_16x16x32_bf16(a1, b1, acc[1][1], 0, 0, 0);
      acc[1][2] = __builtin_amdgcn_mfma_f32_16x16x32_bf16(a1, b2, acc[1][2], 0, 0, 0);
      acc[1][3] = __builtin_amdgcn_mfma_f32_16x16x32_bf16(a1, b3, acc[1][3], 0, 0, 0);
      acc[2][0] = __builtin_amdgcn_mfma_f32_16x16x32_bf16(a2, b0, acc[2][0], 0, 0, 0);
      acc[2][1] = __builtin_amdgcn_mfma_f32_16x16x32_bf16(a2, b1, acc[2][1], 0, 0, 0);
      acc[2][2] = __builtin_amdgcn_mfma_f32_16x16x32_bf16(a2, b2, acc[2][2], 0, 0, 0);
      acc[2][3] = __builtin_amdgcn_mfma_f32_16x16x32_bf16(a2, b3, acc[2][3], 0, 0, 0);
      acc[3][0] = __builtin_amdgcn_mfma_f32_16x16x32_bf16(a3, b0, acc[3][0], 0, 0, 0);
      acc[3][1] = __builtin_amdgcn_mfma_f32_16x16x32_bf16(a3, b1, acc[3][1], 0, 0, 0);
      acc[3][2] = __builtin_amdgcn_mfma_f32_16x16x32_bf16(a3, b2, acc[3][2], 0, 0, 0);
      acc[3][3] = __builtin_amdgcn_mfma_f32_16x16x32_bf16(a3, b3, acc[3][3], 0, 0, 0);
    }
    __syncthreads();
  }
#pragma unroll
  for (int c = 0; c < 4; c++) {
    const int n = wc + c * 16 + l15;
    const float bv = bias[n];
#pragma unroll
    for (int r = 0; r < 4; r++) {
      const int mrow = m0 + wr + r * 16 + quad * 4;
#pragma unroll
      for (int i = 0; i < 4; i++) {
        if (mrow + i < M) out[(size_t)(mrow + i) * D + n] = acc[r][c][i] + bv;
      }
    }
  }
}

extern "C" void kernel_launch(void* const* d_in, const int* in_sizes, int n_in,
                              void* d_out, int out_size, void* d_ws, size_t ws_size,
                              hipStream_t stream) {
  const float* x_user   = (const float*)d_in[0];
  const float* x_item   = (const float*)d_in[1];
  const int*   ei_rates = (const int*)d_in[2];
  const int*   ei_rev   = (const int*)d_in[3];
  const int*   ei_fol   = (const int*)d_in[4];
  const float* Wl_rates = (const float*)d_in[5];
  const float* bl_rates = (const float*)d_in[6];
  const float* Wr_rates = (const float*)d_in[7];
  const float* Wl_rev   = (const float*)d_in[8];
  const float* bl_rev   = (const float*)d_in[9];
  const float* Wr_rev   = (const float*)d_in[10];
  const float* Wl_fol   = (const float*)d_in[11];
  const float* bl_fol   = (const float*)d_in[12];
  const float* Wr_fol   = (const float*)d_in[13];

  const int NU = in_sizes[0] / D;       // 50000
  const int NI = in_sizes[1] / D;       // 50000
  const int E_rates = in_sizes[2] / 2;
  const int E_rev   = in_sizes[3] / 2;
  const int E_fol   = in_sizes[4] / 2;
  const int nbkt = ((NU > NI ? NU : NI) + 127) / 128;   // 391

  // ---- workspace carve-up (byte-based, 16B aligned) ----
  char* wsb = (char*)d_ws;
  size_t off = 0;
  auto take = [&](size_t bytes) {
    char* p = wsb + off;
    off += (bytes + 15) & ~(size_t)15;
    return p;
  };
  int* bhist = (int*)take(3 * NBB * 4);          // zeroed
  const size_t zero_bytes = off;
  int* bbase = (int*)take(3 * NBB * 4);
  int* bcur  = (int*)take(3 * NBB * 4);
  unsigned* part_rates = (unsigned*)take((size_t)E_rates * 4);
  unsigned* part_rev   = (unsigned*)take((size_t)E_rev * 4);
  unsigned* part_fol   = (unsigned*)take((size_t)E_fol * 4);
  unsigned short* xb_user    = (unsigned short*)take((size_t)NU * D * 2);
  unsigned short* xb_item    = (unsigned short*)take((size_t)NI * D * 2);
  unsigned short* mean_rates = (unsigned short*)take((size_t)NI * D * 2);
  unsigned short* mean_rev   = (unsigned short*)take((size_t)NU * D * 2);
  unsigned short* mean_fol   = (unsigned short*)take((size_t)NU * D * 2);
  unsigned short* Wb_user    = (unsigned short*)take(128 * 384 * 2);
  unsigned short* Wb_item    = (unsigned short*)take(128 * 256 * 2);
  float* b_user = (float*)take(128 * 4);
  float* b_item = (float*)take(128 * 4);

  hipMemsetAsync(d_ws, 0, zero_bytes, stream);

  SetupArgs SA;
  SA.xu = x_user; SA.xi = x_item; SA.xbu = xb_user; SA.xbi = xb_item;
  SA.n4u = NU * D / 4; SA.n4i = NI * D / 4;
  SA.nbConv = (SA.n4u + SA.n4i + 255) / 256;
  SA.ei[0] = ei_rates; SA.ne[0] = E_rates; SA.nbh[0] = (E_rates + 2047) / 2048;
  SA.ei[1] = ei_rev;   SA.ne[1] = E_rev;   SA.nbh[1] = (E_rev + 2047) / 2048;
  SA.ei[2] = ei_fol;   SA.ne[2] = E_fol;   SA.nbh[2] = (E_fol + 2047) / 2048;
  SA.nbHist = SA.nbh[0] + SA.nbh[1] + SA.nbh[2];
  SA.bh = bhist;
  SA.Wl_rates = Wl_rates; SA.Wr_rates = Wr_rates; SA.bl_rates = bl_rates;
  SA.Wl_rev = Wl_rev; SA.Wr_rev = Wr_rev; SA.bl_rev = bl_rev;
  SA.Wl_fol = Wl_fol; SA.Wr_fol = Wr_fol; SA.bl_fol = bl_fol;
  SA.Wb_user = Wb_user; SA.Wb_item = Wb_item;
  SA.b_user = b_user; SA.b_item = b_item;
  const int nbPrep = (128 * 384 + 255) / 256;   // 192
  setup_kernel<<<SA.nbConv + SA.nbHist + nbPrep, 256, 0, stream>>>(SA);

  scanb_kernel<<<1, 192, 0, stream>>>(bhist, bbase, bcur, nbkt);

  PArgs P;
  P.ei[0] = ei_rates; P.ne[0] = E_rates; P.nb[0] = (E_rates + 4095) / 4096; P.part[0] = part_rates;
  P.ei[1] = ei_rev;   P.ne[1] = E_rev;   P.nb[1] = (E_rev + 4095) / 4096;   P.part[1] = part_rev;
  P.ei[2] = ei_fol;   P.ne[2] = E_fol;   P.nb[2] = (E_fol + 4095) / 4096;   P.part[2] = part_fol;
  part_kernel<<<P.nb[0] + P.nb[1] + P.nb[2], 256, 0, stream>>>(P, bcur, nbkt);

  BAArgs BA;
  BA.part[0] = part_rates; BA.xb[0] = xb_user; BA.mean[0] = mean_rates; BA.m[0] = NI;
  BA.part[1] = part_rev;   BA.xb[1] = xb_item; BA.mean[1] = mean_rev;   BA.m[1] = NU;
  BA.part[2] = part_fol;   BA.xb[2] = xb_user; BA.mean[2] = mean_fol;   BA.m[2] = NU;
  bagg_kernel<<<3 * nbkt, 256, 0, stream>>>(BA, bbase, nbkt);

  GemmArgs gma;
  gma.su.s[0] = mean_rev;   gma.su.s[1] = mean_fol; gma.su.s[2] = xb_user;
  gma.si.s[0] = mean_rates; gma.si.s[1] = xb_item;  gma.si.s[2] = nullptr;
  gma.wbU = Wb_user; gma.wbI = Wb_item;
  gma.bU = b_user;   gma.bI = b_item;
  gma.outU = (float*)d_out;
  gma.outI = (float*)d_out + (size_t)NU * D;
  gma.MU = NU; gma.MI = NI;
  gma.nbU = (NU + 127) / 128;
  const int nbI = (NI + 127) / 128;
  gemm2_kernel<<<gma.nbU + nbI, 256, 0, stream>>>(gma);
}